// Round 1
// 655.941 us; speedup vs baseline: 1.4076x; 1.4076x over previous
//
#include <hip/hip_runtime.h>
#include <math.h>

typedef unsigned short ushortT;
typedef unsigned int uintT;
typedef __attribute__((ext_vector_type(8))) short short8;
typedef __attribute__((ext_vector_type(4))) float floatx4;

// Problem constants
#define DDIM 256
#define WWIN 64
#define BDIM 8
#define LDIM 8192
#define NWIN 128
#define CHUNK 8
#define NCHUNK 16
#define MAT ((size_t)DDIM * DDIM)

// 16B-slot XOR swizzle within a 128B LDS row (8 slots of 8 bf16 each).
// Spreads the MFMA fragment reads (lanes vary in row, fixed slot) across all
// 8 bank-quads instead of 4 -> hits the LDS b128 service floor.
#define SW8(row, slot) ((((slot) ^ ((row) & 7))) * 8)

__device__ __forceinline__ float dev_sigmoid(float x) {
    return 1.f / (1.f + expf(-x));
}

// f32 -> bf16 round-to-nearest-even
__device__ __forceinline__ ushortT f2b(float f) {
    uintT u = __float_as_uint(f);
    u += 0x7fff + ((u >> 16) & 1);
    return (ushortT)(u >> 16);
}

// ---------------------------------------------------------------------------
// Fused sums GEMM (replaces transpose_keys/transpose_vals + sums_mfma):
//   Out[n][m][e] = sum_{r=0..511} Asrc[l(r)][m] * (gamma[l(r)] * Bsrc[l(r)][e])
// where r = b*64 + w, l(r) = b*LDIM + n*WWIN + w. K-chunk c == batch b.
// Reads f32 inputs directly; transposes + converts to bf16 in LDS.
// Block: 128x128 tile of one window. 4 waves of 64x64 (4x4 16x16 frags).
// grid = NWIN * 2(mq) * 2(nq).
// ---------------------------------------------------------------------------
__global__ __launch_bounds__(256, 2) void sums_fused(
    const float* __restrict__ Asrc,
    const float* __restrict__ Bsrc,
    const float* __restrict__ gammas,
    float* __restrict__ Out) {
    int nq = blockIdx.x & 1;
    int mq = (blockIdx.x >> 1) & 1;
    int n = blockIdx.x >> 2;

    __shared__ __align__(16) ushortT Asm[128 * 64];
    __shared__ __align__(16) ushortT Bsm[128 * 64];

    int t = threadIdx.x;
    int lane = t & 63, wv = t >> 6;
    int wm = (wv & 1) * 64, wn = (wv >> 1) * 64;
    int m16 = lane & 15, g = lane >> 4;

    // staging decomposition: thread covers 4 consecutive rows (r-quad) x 4 d.
    int d0 = (t >> 3) * 4;  // 0..124 step 4 (32 chunks cover 128 d)
    int rqb = t & 7;        // row-quad base; +8*p covers quads 0..15 (64 rows)

    floatx4 acc[4][4];
#pragma unroll
    for (int i = 0; i < 4; i++)
#pragma unroll
        for (int j = 0; j < 4; j++) acc[i][j] = (floatx4)0.f;

    for (int c = 0; c < 8; c++) {
        size_t lbase = (size_t)c * LDIM + n * WWIN;
        __syncthreads();
#pragma unroll
        for (int p = 0; p < 2; p++) {
            int rq = rqb + 8 * p;   // row-quad 0..15
            int r0 = rq * 4;
            const float* Ar = Asrc + (lbase + r0) * DDIM + mq * 128 + d0;
            const float* Br = Bsrc + (lbase + r0) * DDIM + nq * 128 + d0;
            floatx4 a0 = *(const floatx4*)Ar;
            floatx4 a1 = *(const floatx4*)(Ar + DDIM);
            floatx4 a2 = *(const floatx4*)(Ar + 2 * DDIM);
            floatx4 a3 = *(const floatx4*)(Ar + 3 * DDIM);
            floatx4 b0 = *(const floatx4*)Br;
            floatx4 b1 = *(const floatx4*)(Br + DDIM);
            floatx4 b2 = *(const floatx4*)(Br + 2 * DDIM);
            floatx4 b3 = *(const floatx4*)(Br + 3 * DDIM);
            floatx4 gv = *(const floatx4*)(gammas + lbase + r0);
            b0 *= gv[0]; b1 *= gv[1]; b2 *= gv[2]; b3 *= gv[3];
            int slot = rq >> 1;
            int half = (rq & 1) * 4;
#pragma unroll
            for (int j = 0; j < 4; j++) {
                int dr = d0 + j;
                uint2 wa, wb;
                wa.x = (uintT)f2b(a0[j]) | ((uintT)f2b(a1[j]) << 16);
                wa.y = (uintT)f2b(a2[j]) | ((uintT)f2b(a3[j]) << 16);
                wb.x = (uintT)f2b(b0[j]) | ((uintT)f2b(b1[j]) << 16);
                wb.y = (uintT)f2b(b2[j]) | ((uintT)f2b(b3[j]) << 16);
                *(uint2*)&Asm[dr * 64 + SW8(dr, slot) + half] = wa;
                *(uint2*)&Bsm[dr * 64 + SW8(dr, slot) + half] = wb;
            }
        }
        __syncthreads();
#pragma unroll
        for (int ks = 0; ks < 2; ks++) {
            short8 af[4], bq[4];
#pragma unroll
            for (int i = 0; i < 4; i++) {
                int row = wm + i * 16 + m16;
                af[i] = *(const short8*)&Asm[row * 64 + SW8(row, 4 * ks + g)];
            }
#pragma unroll
            for (int j = 0; j < 4; j++) {
                int row = wn + j * 16 + m16;
                bq[j] = *(const short8*)&Bsm[row * 64 + SW8(row, 4 * ks + g)];
            }
#pragma unroll
            for (int i = 0; i < 4; i++)
#pragma unroll
                for (int j = 0; j < 4; j++)
                    acc[i][j] = __builtin_amdgcn_mfma_f32_16x16x32_bf16(
                        af[i], bq[j], acc[i][j], 0, 0, 0);
        }
    }

    float* Ob = Out + (size_t)n * MAT;
#pragma unroll
    for (int i = 0; i < 4; i++)
#pragma unroll
        for (int j = 0; j < 4; j++)
#pragma unroll
            for (int r = 0; r < 4; r++) {
                int row = mq * 128 + wm + i * 16 + g * 4 + r;
                int col = nq * 128 + wn + j * 16 + m16;
                Ob[(size_t)row * DDIM + col] = acc[i][j][r];
            }
}

// ---------------------------------------------------------------------------
// MFMA retrieval: out[l][o] = sum_d q[l][d] * M[n(l)][o][d]
// M read directly from f32 scan output (convert_m removed).
// Block: 128 q-rows x 128 o for one window. grid = NWIN * 4(rp) * 2(op).
// ---------------------------------------------------------------------------
__global__ __launch_bounds__(256, 2) void out_mfma(
    const float* __restrict__ q,
    const float* __restrict__ Ms,
    float* __restrict__ out) {
    int op = blockIdx.x & 1;
    int rp = (blockIdx.x >> 1) & 3;
    int n = blockIdx.x >> 3;

    __shared__ __align__(16) ushortT Qsm[128 * 64];
    __shared__ __align__(16) ushortT Msm[128 * 64];

    int t = threadIdx.x;
    int lane = t & 63, wv = t >> 6;
    int wm = (wv & 1) * 64, wn = (wv >> 1) * 64;
    int m16 = lane & 15, g = lane >> 4;

    const float* Mbase = Ms + (size_t)n * MAT + (size_t)(op * 128) * DDIM;

    floatx4 acc[4][4];
#pragma unroll
    for (int i = 0; i < 4; i++)
#pragma unroll
        for (int j = 0; j < 4; j++) acc[i][j] = (floatx4)0.f;

    for (int c = 0; c < 4; c++) {
        int d0 = c * 64;
        __syncthreads();
        // stage q: 128 rows x 64 d, f32->bf16
#pragma unroll
        for (int p = 0; p < 8; p++) {
            int row = (t >> 4) + p * 16;
            int f4 = t & 15;
            int b = rp * 2 + (row >> 6);
            int l = b * LDIM + n * WWIN + (row & 63);
            floatx4 v = *(const floatx4*)&q[(size_t)l * DDIM + d0 + f4 * 4];
            uint2 o2;
            o2.x = (uintT)f2b(v[0]) | ((uintT)f2b(v[1]) << 16);
            o2.y = (uintT)f2b(v[2]) | ((uintT)f2b(v[3]) << 16);
            *(uint2*)&Qsm[row * 64 + SW8(row, f4 >> 1) + (f4 & 1) * 4] = o2;
        }
        // stage M: 128 o x 64 d, f32->bf16
#pragma unroll
        for (int p = 0; p < 4; p++) {
            int o = (t >> 3) + p * 32;
            int dg = t & 7;
            const floatx4* src =
                (const floatx4*)&Mbase[(size_t)o * DDIM + d0 + dg * 8];
            floatx4 m0 = src[0];
            floatx4 m1 = src[1];
            uint4 w;
            w.x = (uintT)f2b(m0[0]) | ((uintT)f2b(m0[1]) << 16);
            w.y = (uintT)f2b(m0[2]) | ((uintT)f2b(m0[3]) << 16);
            w.z = (uintT)f2b(m1[0]) | ((uintT)f2b(m1[1]) << 16);
            w.w = (uintT)f2b(m1[2]) | ((uintT)f2b(m1[3]) << 16);
            *(uint4*)&Msm[o * 64 + SW8(o, dg)] = w;
        }
        __syncthreads();
#pragma unroll
        for (int ks = 0; ks < 2; ks++) {
            short8 af[4], bq[4];
#pragma unroll
            for (int i = 0; i < 4; i++) {
                int row = wm + i * 16 + m16;
                af[i] = *(const short8*)&Qsm[row * 64 + SW8(row, 4 * ks + g)];
            }
#pragma unroll
            for (int j = 0; j < 4; j++) {
                int row = wn + j * 16 + m16;
                bq[j] = *(const short8*)&Msm[row * 64 + SW8(row, 4 * ks + g)];
            }
#pragma unroll
            for (int i = 0; i < 4; i++)
#pragma unroll
                for (int j = 0; j < 4; j++)
                    acc[i][j] = __builtin_amdgcn_mfma_f32_16x16x32_bf16(
                        af[i], bq[j], acc[i][j], 0, 0, 0);
        }
    }

#pragma unroll
    for (int i = 0; i < 4; i++)
#pragma unroll
        for (int r = 0; r < 4; r++) {
            int row = wm + i * 16 + g * 4 + r;
            int b = rp * 2 + (row >> 6);
            size_t l = (size_t)b * LDIM + n * WWIN + (row & 63);
#pragma unroll
            for (int j = 0; j < 4; j++) {
                int col = op * 128 + wn + j * 16 + m16;
                out[l * DDIM + col] = acc[i][j][r];
            }
        }
}

// ---------------------------------------------------------------------------
// Scan (f32 machinery)
// ---------------------------------------------------------------------------
__device__ __forceinline__ void mm_tile16(const float* __restrict__ A,
                                          const float* __restrict__ B,
                                          const float* __restrict__ Add,
                                          float* __restrict__ Dst,
                                          int row0, float scale, float sgn) {
    __shared__ float Ash[16][33];
    __shared__ float Bsh[32][256];

    int t = threadIdx.x;
    int tcol = t & 63;
    int trow = t >> 6;

    float acc[4][4];
#pragma unroll
    for (int i = 0; i < 4; i++)
#pragma unroll
        for (int j = 0; j < 4; j++) acc[i][j] = 0.f;

    for (int k0 = 0; k0 < DDIM; k0 += 32) {
        __syncthreads();
        {
            int row = t >> 4;
            int kk = (t & 15) * 2;
            float2 v = *(const float2*)&A[(size_t)(row0 + row) * DDIM + k0 + kk];
            Ash[row][kk] = v.x;
            Ash[row][kk + 1] = v.y;
        }
#pragma unroll
        for (int p = 0; p < 8; p++) {
            int row = (t >> 6) + p * 4;
            int c4 = (t & 63) * 4;
            *(float4*)&Bsh[row][c4] =
                *(const float4*)&B[(size_t)(k0 + row) * DDIM + c4];
        }
        __syncthreads();
#pragma unroll
        for (int kk = 0; kk < 32; kk++) {
            float4 bv = *(const float4*)&Bsh[kk][tcol * 4];
#pragma unroll
            for (int i = 0; i < 4; i++) {
                float av = Ash[trow * 4 + i][kk];
                acc[i][0] += av * bv.x;
                acc[i][1] += av * bv.y;
                acc[i][2] += av * bv.z;
                acc[i][3] += av * bv.w;
            }
        }
    }

#pragma unroll
    for (int i = 0; i < 4; i++) {
        int r = row0 + trow * 4 + i;
        float4 av = *(const float4*)&A[(size_t)r * DDIM + tcol * 4];
        float4 o;
        o.x = scale * av.x + sgn * acc[i][0];
        o.y = scale * av.y + sgn * acc[i][1];
        o.z = scale * av.z + sgn * acc[i][2];
        o.w = scale * av.w + sgn * acc[i][3];
        if (Add) {
            float4 ad = *(const float4*)&Add[(size_t)r * DDIM + tcol * 4];
            o.x += ad.x; o.y += ad.y; o.z += ad.z; o.w += ad.w;
        }
        *(float4*)&Dst[(size_t)r * DDIM + tcol * 4] = o;
    }
}

__device__ __forceinline__ void copy_tile16(const float* __restrict__ src,
                                            float* __restrict__ dst, int row0) {
    int t = threadIdx.x;
    size_t base = (size_t)(row0 + (t >> 4)) * DDIM + (t & 15) * 16;
#pragma unroll
    for (int i = 0; i < 4; i++)
        *(float4*)&dst[base + i * 4] = *(const float4*)&src[base + i * 4];
}

__global__ void pinit_kernel(const float* __restrict__ Skk,
                             float* __restrict__ P,
                             const float* __restrict__ alpha_raw) {
    float a = dev_sigmoid(alpha_raw[0]);
    int cm = blockIdx.x >> 6;
    size_t e = (size_t)(blockIdx.x & 63) * 1024 + threadIdx.x * 4;
    size_t base = (size_t)(cm * CHUNK) * MAT + e;
    int row = (int)(e >> 8);
    int col = (int)(e & 255);
    float4 v = *(const float4*)&Skk[base];
    float4 o;
    o.x = ((row == col)     ? a : 0.f) - v.x;
    o.y = ((row == col + 1) ? a : 0.f) - v.y;
    o.z = ((row == col + 2) ? a : 0.f) - v.z;
    o.w = ((row == col + 3) ? a : 0.f) - v.w;
    *(float4*)&P[base] = o;
}

__global__ void phase1_kernel(const float* __restrict__ Skk,
                              float* __restrict__ Q,
                              float* __restrict__ P,
                              const float* __restrict__ alpha_raw,
                              int j) {
    float a = dev_sigmoid(alpha_raw[0]);
    int tile = blockIdx.x & 15;
    int idx = blockIdx.x >> 4;
    int chunk = idx >> 1;
    int target = idx & 1;
    int n = chunk * CHUNK + j;
    const float* Bm = Skk + (size_t)n * MAT;
    if (target == 0) {
        mm_tile16(P + (size_t)(n - 1) * MAT, Bm, nullptr,
                  P + (size_t)n * MAT, tile * 16, a, -1.f);
    } else {
        float* d = Q + (size_t)n * MAT;
        mm_tile16(Q + (size_t)(n - 1) * MAT, Bm, d, d, tile * 16, a, -1.f);
    }
}

// ---------------------------------------------------------------------------
// Kogge-Stone tree over the 16 chunk carries (replaces 15 sequential tiny
// phase2 launches with 4 well-filled ones). Operator:
//   Q'_c = Q_{c-s} * P_c + Q_c ;  P'_c = P_{c-s} * P_c   (c >= s; copy else)
// Buffers ping-pong; final step (s=8, Q-only) writes main Q tails.
// ---------------------------------------------------------------------------
__global__ void ks_kernel(const float* __restrict__ srcQ,
                          const float* __restrict__ srcP,
                          float* __restrict__ dstQ,
                          float* __restrict__ dstP,
                          size_t sQs, size_t sPs, size_t dQs, size_t dPs,
                          int s, int qonly) {
    int tile = blockIdx.x & 15;
    int idx = blockIdx.x >> 4;
    int kind = qonly ? 0 : (idx & 1);
    int c = qonly ? idx : (idx >> 1);
    if (kind == 0) {
        float* D = dstQ + (size_t)c * dQs;
        if (c >= s) {
            mm_tile16(srcQ + (size_t)(c - s) * sQs, srcP + (size_t)c * sPs,
                      srcQ + (size_t)c * sQs, D, tile * 16, 0.f, 1.f);
        } else {
            copy_tile16(srcQ + (size_t)c * sQs, D, tile * 16);
        }
    } else {
        float* D = dstP + (size_t)c * dPs;
        if (c >= s) {
            mm_tile16(srcP + (size_t)(c - s) * sPs, srcP + (size_t)c * sPs,
                      nullptr, D, tile * 16, 0.f, 1.f);
        } else {
            copy_tile16(srcP + (size_t)c * sPs, D, tile * 16);
        }
    }
}

__global__ void phase3_kernel(float* __restrict__ Q,
                              const float* __restrict__ P) {
    int tile = blockIdx.x & 15;
    int w = blockIdx.x >> 4;
    int c = 1 + w / (CHUNK - 1);
    int j = w - (c - 1) * (CHUNK - 1);
    int n = c * CHUNK + j;
    int s = c * CHUNK - 1;
    float* d = Q + (size_t)n * MAT;
    mm_tile16(Q + (size_t)s * MAT, P + (size_t)n * MAT, d, d,
              tile * 16, 0.f, 1.f);
}

// ---------------------------------------------------------------------------
extern "C" void kernel_launch(void* const* d_in, const int* in_sizes, int n_in,
                              void* d_out, int out_size, void* d_ws, size_t ws_size,
                              hipStream_t stream) {
    const float* keys    = (const float*)d_in[0];
    const float* values  = (const float*)d_in[1];
    const float* queries = (const float*)d_in[2];
    const float* gammas  = (const float*)d_in[3];
    const float* alpha   = (const float*)d_in[4];
    float* outp = (float*)d_out;

    // Workspace layout (112 MB peak):
    //  A [0,32M):   Skk f32
    //  B [32,64M):  Q f32 (Svk -> prefix -> final Ms)
    //  C [64,96M):  P f32
    //  D [96,112M): KS ping-pong tail buffers (T1Q,T1P,T2Q,T2P, 4MB each)
    char* ws = (char*)d_ws;
    float* Skk = (float*)ws;
    float* Q   = (float*)(ws + (size_t)32 * 1024 * 1024);
    float* P   = (float*)(ws + (size_t)64 * 1024 * 1024);
    char*  rD  = ws + (size_t)96 * 1024 * 1024;
    float* T1Q = (float*)rD;
    float* T1P = (float*)(rD + (size_t)4 * 1024 * 1024);
    float* T2Q = (float*)(rD + (size_t)8 * 1024 * 1024);
    float* T2P = (float*)(rD + (size_t)12 * 1024 * 1024);

    // 1) Skk = sum gamma k k^T  (fused transpose+convert+GEMM)
    sums_fused<<<NWIN * 4, 256, 0, stream>>>(keys, keys, gammas, Skk);
    // 2) Svk = sum gamma v k^T -> Q
    sums_fused<<<NWIN * 4, 256, 0, stream>>>(values, keys, gammas, Q);

    // 3) scan: chunk-local pass
    pinit_kernel<<<1024, 256, 0, stream>>>(Skk, P, alpha);
    for (int j = 1; j < CHUNK; j++)
        phase1_kernel<<<NCHUNK * 2 * 16, 256, 0, stream>>>(Skk, Q, P, alpha, j);

    // 4) cross-chunk Kogge-Stone on the 16 tails (e_c = 8c+7)
    ks_kernel<<<32 * 16, 256, 0, stream>>>(Q + 7 * MAT, P + 7 * MAT, T1Q, T1P,
                                           8 * MAT, 8 * MAT, MAT, MAT, 1, 0);
    ks_kernel<<<32 * 16, 256, 0, stream>>>(T1Q, T1P, T2Q, T2P,
                                           MAT, MAT, MAT, MAT, 2, 0);
    ks_kernel<<<32 * 16, 256, 0, stream>>>(T2Q, T2P, T1Q, T1P,
                                           MAT, MAT, MAT, MAT, 4, 0);
    ks_kernel<<<16 * 16, 256, 0, stream>>>(T1Q, T1P, Q + 7 * MAT, nullptr,
                                           MAT, MAT, 8 * MAT, 0, 8, 1);

    // 5) broadcast tails into non-tail windows
    phase3_kernel<<<(NCHUNK - 1) * (CHUNK - 1) * 16, 256, 0, stream>>>(Q, P);

    // 6) retrieval (M converted f32->bf16 in-flight; convert_m removed)
    out_mfma<<<NWIN * 8, 256, 0, stream>>>(queries, Q, outp);
}

// Round 2
// 617.168 us; speedup vs baseline: 1.4960x; 1.0628x over previous
//
#include <hip/hip_runtime.h>
#include <math.h>

typedef unsigned short ushortT;
typedef unsigned int uintT;
typedef __attribute__((ext_vector_type(8))) short short8;
typedef __attribute__((ext_vector_type(4))) float floatx4;

// Problem constants
#define DDIM 256
#define WWIN 64
#define BDIM 8
#define LDIM 8192
#define NWIN 128
#define CHUNK 8
#define NCHUNK 16
#define MAT ((size_t)DDIM * DDIM)

// 16B-slot XOR swizzle within a 128B LDS row (8 slots of 8 bf16 each).
#define SW8(row, slot) ((((slot) ^ ((row) & 7))) * 8)

__device__ __forceinline__ float dev_sigmoid(float x) {
    return 1.f / (1.f + expf(-x));
}

// f32 -> bf16 round-to-nearest-even
__device__ __forceinline__ ushortT f2b(float f) {
    uintT u = __float_as_uint(f);
    u += 0x7fff + ((u >> 16) & 1);
    return (ushortT)(u >> 16);
}

// ---------------------------------------------------------------------------
// Fused sums GEMM:
//   Out[n][m][e] = sum_{r=0..511} Asrc[l(r)][m] * (gamma[l(r)] * Bsrc[l(r)][e])
// A-side + gammas register-prefetched across the K-chunk loop (T14); B inline.
// When Pinit != nullptr, chunk-start windows also emit P = a*I - Out.
// Block: 128x128 tile of one window, 4 waves. grid = NWIN*2*2.
// ---------------------------------------------------------------------------
__global__ __launch_bounds__(256, 2) void sums_fused(
    const float* __restrict__ Asrc,
    const float* __restrict__ Bsrc,
    const float* __restrict__ gammas,
    float* __restrict__ Out,
    float* __restrict__ Pinit,
    const float* __restrict__ alpha_raw) {
    int nq = blockIdx.x & 1;
    int mq = (blockIdx.x >> 1) & 1;
    int n = blockIdx.x >> 2;

    __shared__ __align__(16) ushortT Asm[128 * 64];
    __shared__ __align__(16) ushortT Bsm[128 * 64];

    int t = threadIdx.x;
    int lane = t & 63, wv = t >> 6;
    int wm = (wv & 1) * 64, wn = (wv >> 1) * 64;
    int m16 = lane & 15, g = lane >> 4;

    // staging decomposition: thread covers 4 consecutive rows (r-quad) x 4 d.
    int d0 = (t >> 3) * 4;  // 0..124 step 4
    int rqb = t & 7;        // row-quad base; +8*p covers quads 0..15

    floatx4 acc[4][4];
#pragma unroll
    for (int i = 0; i < 4; i++)
#pragma unroll
        for (int j = 0; j < 4; j++) acc[i][j] = (floatx4)0.f;

    // prefetch registers: A-side rows + gammas for the NEXT chunk
    floatx4 pa[2][4], pgv[2];
    {
        size_t lbase = (size_t)n * WWIN;
#pragma unroll
        for (int p = 0; p < 2; p++) {
            int r0 = (rqb + 8 * p) * 4;
            const float* Ar = Asrc + (lbase + r0) * DDIM + mq * 128 + d0;
            pa[p][0] = *(const floatx4*)Ar;
            pa[p][1] = *(const floatx4*)(Ar + DDIM);
            pa[p][2] = *(const floatx4*)(Ar + 2 * DDIM);
            pa[p][3] = *(const floatx4*)(Ar + 3 * DDIM);
            pgv[p] = *(const floatx4*)(gammas + lbase + r0);
        }
    }

    for (int c = 0; c < 8; c++) {
        size_t lbase = (size_t)c * LDIM + n * WWIN;
        __syncthreads();
#pragma unroll
        for (int p = 0; p < 2; p++) {
            int rq = rqb + 8 * p;
            int r0 = rq * 4;
            const float* Br = Bsrc + (lbase + r0) * DDIM + nq * 128 + d0;
            floatx4 b0 = *(const floatx4*)Br;
            floatx4 b1 = *(const floatx4*)(Br + DDIM);
            floatx4 b2 = *(const floatx4*)(Br + 2 * DDIM);
            floatx4 b3 = *(const floatx4*)(Br + 3 * DDIM);
            floatx4 gv = pgv[p];
            b0 *= gv[0]; b1 *= gv[1]; b2 *= gv[2]; b3 *= gv[3];
            int slot = rq >> 1;
            int half = (rq & 1) * 4;
#pragma unroll
            for (int j = 0; j < 4; j++) {
                int dr = d0 + j;
                uint2 wa, wb;
                wa.x = (uintT)f2b(pa[p][0][j]) | ((uintT)f2b(pa[p][1][j]) << 16);
                wa.y = (uintT)f2b(pa[p][2][j]) | ((uintT)f2b(pa[p][3][j]) << 16);
                wb.x = (uintT)f2b(b0[j]) | ((uintT)f2b(b1[j]) << 16);
                wb.y = (uintT)f2b(b2[j]) | ((uintT)f2b(b3[j]) << 16);
                *(uint2*)&Asm[dr * 64 + SW8(dr, slot) + half] = wa;
                *(uint2*)&Bsm[dr * 64 + SW8(dr, slot) + half] = wb;
            }
        }
        // issue next chunk's A/gamma loads; they stay in flight across the
        // barrier + MFMA phase (issued youngest -> M-side waits don't drain them)
        if (c < 7) {
            size_t lb2 = lbase + LDIM;
#pragma unroll
            for (int p = 0; p < 2; p++) {
                int r0 = (rqb + 8 * p) * 4;
                const float* Ar = Asrc + (lb2 + r0) * DDIM + mq * 128 + d0;
                pa[p][0] = *(const floatx4*)Ar;
                pa[p][1] = *(const floatx4*)(Ar + DDIM);
                pa[p][2] = *(const floatx4*)(Ar + 2 * DDIM);
                pa[p][3] = *(const floatx4*)(Ar + 3 * DDIM);
                pgv[p] = *(const floatx4*)(gammas + lb2 + r0);
            }
        }
        __syncthreads();
#pragma unroll
        for (int ks = 0; ks < 2; ks++) {
            short8 af[4], bq[4];
#pragma unroll
            for (int i = 0; i < 4; i++) {
                int row = wm + i * 16 + m16;
                af[i] = *(const short8*)&Asm[row * 64 + SW8(row, 4 * ks + g)];
            }
#pragma unroll
            for (int j = 0; j < 4; j++) {
                int row = wn + j * 16 + m16;
                bq[j] = *(const short8*)&Bsm[row * 64 + SW8(row, 4 * ks + g)];
            }
#pragma unroll
            for (int i = 0; i < 4; i++)
#pragma unroll
                for (int j = 0; j < 4; j++)
                    acc[i][j] = __builtin_amdgcn_mfma_f32_16x16x32_bf16(
                        af[i], bq[j], acc[i][j], 0, 0, 0);
        }
    }

    float* Ob = Out + (size_t)n * MAT;
    bool doP = (Pinit != nullptr) && ((n & (CHUNK - 1)) == 0);
    float aSig = doP ? dev_sigmoid(alpha_raw[0]) : 0.f;
#pragma unroll
    for (int i = 0; i < 4; i++)
#pragma unroll
        for (int j = 0; j < 4; j++)
#pragma unroll
            for (int r = 0; r < 4; r++) {
                int row = mq * 128 + wm + i * 16 + g * 4 + r;
                int col = nq * 128 + wn + j * 16 + m16;
                float v = acc[i][j][r];
                Ob[(size_t)row * DDIM + col] = v;
                if (doP) {
                    float* Pb = Pinit + (size_t)n * MAT;
                    Pb[(size_t)row * DDIM + col] =
                        ((row == col) ? aSig : 0.f) - v;
                }
            }
}

// ---------------------------------------------------------------------------
// MFMA retrieval: out[l][o] = sum_d q[l][d] * M[n(l)][o][d]
// q tile register-prefetched across the d-chunk loop (T14); M inline (L2/L3-hot).
// Block: 128 q-rows x 128 o for one window. grid = NWIN * 4(rp) * 2(op).
// ---------------------------------------------------------------------------
__global__ __launch_bounds__(256, 2) void out_mfma(
    const float* __restrict__ q,
    const float* __restrict__ Ms,
    float* __restrict__ out) {
    int op = blockIdx.x & 1;
    int rp = (blockIdx.x >> 1) & 3;
    int n = blockIdx.x >> 3;

    __shared__ __align__(16) ushortT Qsm[128 * 64];
    __shared__ __align__(16) ushortT Msm[128 * 64];

    int t = threadIdx.x;
    int lane = t & 63, wv = t >> 6;
    int wm = (wv & 1) * 64, wn = (wv >> 1) * 64;
    int m16 = lane & 15, g = lane >> 4;
    int f4 = t & 15;

    const float* Mbase = Ms + (size_t)n * MAT + (size_t)(op * 128) * DDIM;

    floatx4 acc[4][4];
#pragma unroll
    for (int i = 0; i < 4; i++)
#pragma unroll
        for (int j = 0; j < 4; j++) acc[i][j] = (floatx4)0.f;

    // per-thread q source addresses (row varies with p)
    floatx4 qv[8];
    {
#pragma unroll
        for (int p = 0; p < 8; p++) {
            int row = (t >> 4) + p * 16;
            int b = rp * 2 + (row >> 6);
            int l = b * LDIM + n * WWIN + (row & 63);
            qv[p] = *(const floatx4*)&q[(size_t)l * DDIM + f4 * 4];
        }
    }

    for (int c = 0; c < 4; c++) {
        int d0 = c * 64;
        __syncthreads();
        // write prefetched q tile (f32->bf16) into LDS
#pragma unroll
        for (int p = 0; p < 8; p++) {
            int row = (t >> 4) + p * 16;
            uint2 o2;
            o2.x = (uintT)f2b(qv[p][0]) | ((uintT)f2b(qv[p][1]) << 16);
            o2.y = (uintT)f2b(qv[p][2]) | ((uintT)f2b(qv[p][3]) << 16);
            *(uint2*)&Qsm[row * 64 + SW8(row, f4 >> 1) + (f4 & 1) * 4] = o2;
        }
        // stage M inline: 128 o x 64 d, f32->bf16
#pragma unroll
        for (int p = 0; p < 4; p++) {
            int o = (t >> 3) + p * 32;
            int dg = t & 7;
            const floatx4* src =
                (const floatx4*)&Mbase[(size_t)o * DDIM + d0 + dg * 8];
            floatx4 m0 = src[0];
            floatx4 m1 = src[1];
            uint4 w;
            w.x = (uintT)f2b(m0[0]) | ((uintT)f2b(m0[1]) << 16);
            w.y = (uintT)f2b(m0[2]) | ((uintT)f2b(m0[3]) << 16);
            w.z = (uintT)f2b(m1[0]) | ((uintT)f2b(m1[1]) << 16);
            w.w = (uintT)f2b(m1[2]) | ((uintT)f2b(m1[3]) << 16);
            *(uint4*)&Msm[o * 64 + SW8(o, dg)] = w;
        }
        // issue next d-chunk's q loads (youngest in flight across MFMA phase)
        if (c < 3) {
            int d1 = d0 + 64;
#pragma unroll
            for (int p = 0; p < 8; p++) {
                int row = (t >> 4) + p * 16;
                int b = rp * 2 + (row >> 6);
                int l = b * LDIM + n * WWIN + (row & 63);
                qv[p] = *(const floatx4*)&q[(size_t)l * DDIM + d1 + f4 * 4];
            }
        }
        __syncthreads();
#pragma unroll
        for (int ks = 0; ks < 2; ks++) {
            short8 af[4], bq[4];
#pragma unroll
            for (int i = 0; i < 4; i++) {
                int row = wm + i * 16 + m16;
                af[i] = *(const short8*)&Qsm[row * 64 + SW8(row, 4 * ks + g)];
            }
#pragma unroll
            for (int j = 0; j < 4; j++) {
                int row = wn + j * 16 + m16;
                bq[j] = *(const short8*)&Msm[row * 64 + SW8(row, 4 * ks + g)];
            }
#pragma unroll
            for (int i = 0; i < 4; i++)
#pragma unroll
                for (int j = 0; j < 4; j++)
                    acc[i][j] = __builtin_amdgcn_mfma_f32_16x16x32_bf16(
                        af[i], bq[j], acc[i][j], 0, 0, 0);
        }
    }

#pragma unroll
    for (int i = 0; i < 4; i++)
#pragma unroll
        for (int r = 0; r < 4; r++) {
            int row = wm + i * 16 + g * 4 + r;
            int b = rp * 2 + (row >> 6);
            size_t l = (size_t)b * LDIM + n * WWIN + (row & 63);
#pragma unroll
            for (int j = 0; j < 4; j++) {
                int col = op * 128 + wn + j * 16 + m16;
                out[l * DDIM + col] = acc[i][j][r];
            }
        }
}

// ---------------------------------------------------------------------------
// Scan (f32 machinery)
// ---------------------------------------------------------------------------
__device__ __forceinline__ void mm_tile16(const float* __restrict__ A,
                                          const float* __restrict__ B,
                                          const float* __restrict__ Add,
                                          float* __restrict__ Dst,
                                          int row0, float scale, float sgn) {
    __shared__ float Ash[16][33];
    __shared__ float Bsh[32][256];

    int t = threadIdx.x;
    int tcol = t & 63;
    int trow = t >> 6;

    float acc[4][4];
#pragma unroll
    for (int i = 0; i < 4; i++)
#pragma unroll
        for (int j = 0; j < 4; j++) acc[i][j] = 0.f;

    for (int k0 = 0; k0 < DDIM; k0 += 32) {
        __syncthreads();
        {
            int row = t >> 4;
            int kk = (t & 15) * 2;
            float2 v = *(const float2*)&A[(size_t)(row0 + row) * DDIM + k0 + kk];
            Ash[row][kk] = v.x;
            Ash[row][kk + 1] = v.y;
        }
#pragma unroll
        for (int p = 0; p < 8; p++) {
            int row = (t >> 6) + p * 4;
            int c4 = (t & 63) * 4;
            *(float4*)&Bsh[row][c4] =
                *(const float4*)&B[(size_t)(k0 + row) * DDIM + c4];
        }
        __syncthreads();
#pragma unroll
        for (int kk = 0; kk < 32; kk++) {
            float4 bv = *(const float4*)&Bsh[kk][tcol * 4];
#pragma unroll
            for (int i = 0; i < 4; i++) {
                float av = Ash[trow * 4 + i][kk];
                acc[i][0] += av * bv.x;
                acc[i][1] += av * bv.y;
                acc[i][2] += av * bv.z;
                acc[i][3] += av * bv.w;
            }
        }
    }

#pragma unroll
    for (int i = 0; i < 4; i++) {
        int r = row0 + trow * 4 + i;
        float4 av = *(const float4*)&A[(size_t)r * DDIM + tcol * 4];
        float4 o;
        o.x = scale * av.x + sgn * acc[i][0];
        o.y = scale * av.y + sgn * acc[i][1];
        o.z = scale * av.z + sgn * acc[i][2];
        o.w = scale * av.w + sgn * acc[i][3];
        if (Add) {
            float4 ad = *(const float4*)&Add[(size_t)r * DDIM + tcol * 4];
            o.x += ad.x; o.y += ad.y; o.z += ad.z; o.w += ad.w;
        }
        *(float4*)&Dst[(size_t)r * DDIM + tcol * 4] = o;
    }
}

__device__ __forceinline__ void copy_tile16(const float* __restrict__ src,
                                            float* __restrict__ dst, int row0) {
    int t = threadIdx.x;
    size_t base = (size_t)(row0 + (t >> 4)) * DDIM + (t & 15) * 16;
#pragma unroll
    for (int i = 0; i < 4; i++)
        *(float4*)&dst[base + i * 4] = *(const float4*)&src[base + i * 4];
}

__global__ void phase1_kernel(const float* __restrict__ Skk,
                              float* __restrict__ Q,
                              float* __restrict__ P,
                              const float* __restrict__ alpha_raw,
                              int j) {
    float a = dev_sigmoid(alpha_raw[0]);
    int tile = blockIdx.x & 15;
    int idx = blockIdx.x >> 4;
    int chunk = idx >> 1;
    int target = idx & 1;
    int n = chunk * CHUNK + j;
    const float* Bm = Skk + (size_t)n * MAT;
    if (target == 0) {
        mm_tile16(P + (size_t)(n - 1) * MAT, Bm, nullptr,
                  P + (size_t)n * MAT, tile * 16, a, -1.f);
    } else {
        float* d = Q + (size_t)n * MAT;
        mm_tile16(Q + (size_t)(n - 1) * MAT, Bm, d, d, tile * 16, a, -1.f);
    }
}

// ---------------------------------------------------------------------------
// Kogge-Stone tree over the 16 chunk carries. Operator:
//   Q'_c = Q_{c-s} * P_c + Q_c ;  P'_c = P_{c-s} * P_c   (c >= s; copy else)
// ---------------------------------------------------------------------------
__global__ void ks_kernel(const float* __restrict__ srcQ,
                          const float* __restrict__ srcP,
                          float* __restrict__ dstQ,
                          float* __restrict__ dstP,
                          size_t sQs, size_t sPs, size_t dQs, size_t dPs,
                          int s, int qonly) {
    int tile = blockIdx.x & 15;
    int idx = blockIdx.x >> 4;
    int kind = qonly ? 0 : (idx & 1);
    int c = qonly ? idx : (idx >> 1);
    if (kind == 0) {
        float* D = dstQ + (size_t)c * dQs;
        if (c >= s) {
            mm_tile16(srcQ + (size_t)(c - s) * sQs, srcP + (size_t)c * sPs,
                      srcQ + (size_t)c * sQs, D, tile * 16, 0.f, 1.f);
        } else {
            copy_tile16(srcQ + (size_t)c * sQs, D, tile * 16);
        }
    } else {
        float* D = dstP + (size_t)c * dPs;
        if (c >= s) {
            mm_tile16(srcP + (size_t)(c - s) * sPs, srcP + (size_t)c * sPs,
                      nullptr, D, tile * 16, 0.f, 1.f);
        } else {
            copy_tile16(srcP + (size_t)c * sPs, D, tile * 16);
        }
    }
}

__global__ void phase3_kernel(float* __restrict__ Q,
                              const float* __restrict__ P) {
    int tile = blockIdx.x & 15;
    int w = blockIdx.x >> 4;
    int c = 1 + w / (CHUNK - 1);
    int j = w - (c - 1) * (CHUNK - 1);
    int n = c * CHUNK + j;
    int s = c * CHUNK - 1;
    float* d = Q + (size_t)n * MAT;
    mm_tile16(Q + (size_t)s * MAT, P + (size_t)n * MAT, d, d,
              tile * 16, 0.f, 1.f);
}

// ---------------------------------------------------------------------------
extern "C" void kernel_launch(void* const* d_in, const int* in_sizes, int n_in,
                              void* d_out, int out_size, void* d_ws, size_t ws_size,
                              hipStream_t stream) {
    const float* keys    = (const float*)d_in[0];
    const float* values  = (const float*)d_in[1];
    const float* queries = (const float*)d_in[2];
    const float* gammas  = (const float*)d_in[3];
    const float* alpha   = (const float*)d_in[4];
    float* outp = (float*)d_out;

    // Workspace layout (112 MB peak):
    //  A [0,32M):   Skk f32
    //  B [32,64M):  Q f32 (Svk -> prefix -> final Ms)
    //  C [64,96M):  P f32
    //  D [96,112M): KS ping-pong tail buffers (T1Q,T1P,T2Q,T2P, 4MB each)
    char* ws = (char*)d_ws;
    float* Skk = (float*)ws;
    float* Q   = (float*)(ws + (size_t)32 * 1024 * 1024);
    float* P   = (float*)(ws + (size_t)64 * 1024 * 1024);
    char*  rD  = ws + (size_t)96 * 1024 * 1024;
    float* T1Q = (float*)rD;
    float* T1P = (float*)(rD + (size_t)4 * 1024 * 1024);
    float* T2Q = (float*)(rD + (size_t)8 * 1024 * 1024);
    float* T2P = (float*)(rD + (size_t)12 * 1024 * 1024);

    // 1) Skk = sum gamma k k^T ; chunk-start blocks also emit P = aI - Skk
    sums_fused<<<NWIN * 4, 256, 0, stream>>>(keys, keys, gammas, Skk, P, alpha);
    // 2) Svk = sum gamma v k^T -> Q
    sums_fused<<<NWIN * 4, 256, 0, stream>>>(values, keys, gammas, Q, nullptr,
                                             alpha);

    // 3) scan: chunk-local pass
    for (int j = 1; j < CHUNK; j++)
        phase1_kernel<<<NCHUNK * 2 * 16, 256, 0, stream>>>(Skk, Q, P, alpha, j);

    // 4) cross-chunk Kogge-Stone on the 16 tails (e_c = 8c+7)
    ks_kernel<<<32 * 16, 256, 0, stream>>>(Q + 7 * MAT, P + 7 * MAT, T1Q, T1P,
                                           8 * MAT, 8 * MAT, MAT, MAT, 1, 0);
    ks_kernel<<<32 * 16, 256, 0, stream>>>(T1Q, T1P, T2Q, T2P,
                                           MAT, MAT, MAT, MAT, 2, 0);
    ks_kernel<<<32 * 16, 256, 0, stream>>>(T2Q, T2P, T1Q, T1P,
                                           MAT, MAT, MAT, MAT, 4, 0);
    ks_kernel<<<16 * 16, 256, 0, stream>>>(T1Q, T1P, Q + 7 * MAT, nullptr,
                                           MAT, MAT, 8 * MAT, 0, 8, 1);

    // 5) broadcast tails into non-tail windows
    phase3_kernel<<<(NCHUNK - 1) * (CHUNK - 1) * 16, 256, 0, stream>>>(Q, P);

    // 6) retrieval (M converted f32->bf16 in-flight)
    out_mfma<<<NWIN * 8, 256, 0, stream>>>(queries, Q, outp);
}